// Round 2
// baseline (396.110 us; speedup 1.0000x reference)
//
#include <hip/hip_runtime.h>
#include <hip/hip_bf16.h>
#include <math.h>

#define S 1024
#define D 1024
#define P 2816
#define R 64
#define E 8
#define M 16
#define NITD (P / 64)          // 44 k-iters in k_down (full K, no split)
#define ACH ((E * P * R) / 8)  // 180224 adapter short8-chunks

typedef __attribute__((ext_vector_type(8))) short short8;   // 8 bf16 (4 VGPRs)
typedef __attribute__((ext_vector_type(4))) float floatx4;  // MFMA acc

static __device__ inline unsigned short f2bf(float f) {
  __hip_bfloat16 h = __float2bfloat16(f);
  return *reinterpret_cast<unsigned short*>(&h);
}
static __device__ inline short8 pack8(float4 a, float4 b) {
  short8 v;
  v[0] = f2bf(a.x); v[1] = f2bf(a.y); v[2] = f2bf(a.z); v[3] = f2bf(a.w);
  v[4] = f2bf(b.x); v[5] = f2bf(b.y); v[6] = f2bf(b.z); v[7] = f2bf(b.w);
  return v;
}

// ---------------------------------------------------------------------------
// K1 (fused pre-pass), grid 256 x 256:
//  - counting sort (block 0)
//  - softmax alphas + mixed bases, written TRANSPOSED: mxT[e][n=r|64+r][d] bf16
//  - H -> bf16 (Hbf), adapters -> bf16 (Aubf/Agbf)
// NO zeroing: k_t and k_down are now full-K with direct stores (K=1 routing
// means out rows are disjoint across experts -> no atomics anywhere).
// ---------------------------------------------------------------------------
__global__ __launch_bounds__(256) void k_pre(
    const float* __restrict__ up_logits, const float* __restrict__ gate_logits,
    const float* __restrict__ up_bank, const float* __restrict__ gate_bank,
    const float* __restrict__ H, const float* __restrict__ Aup,
    const float* __restrict__ Agate, const int* __restrict__ idx,
    unsigned short* __restrict__ Hbf, unsigned short* __restrict__ mxT,
    unsigned short* __restrict__ Aubf, unsigned short* __restrict__ Agbf,
    int* __restrict__ perm, int* __restrict__ offs) {
  int b = blockIdx.x, t = threadIdx.x;
  int g = b * 256 + t;

  if (b == 0) {  // counting sort, 4 tokens/thread
    __shared__ int hist[E];
    __shared__ int basearr[E];
    if (t < E) hist[t] = 0;
    __syncthreads();
    int e4[4];
#pragma unroll
    for (int j = 0; j < 4; ++j) {
      e4[j] = idx[t + j * 256];
      atomicAdd(&hist[e4[j]], 1);
    }
    __syncthreads();
    if (t == 0) {
      int run = 0;
      for (int i = 0; i < E; ++i) { basearr[i] = run; offs[i] = run; run += hist[i]; }
      offs[E] = S;
    }
    __syncthreads();
#pragma unroll
    for (int j = 0; j < 4; ++j) {
      int pos = atomicAdd(&basearr[e4[j]], 1);
      perm[pos] = t + j * 256;
    }
  }

  // H -> bf16, 16 elems/thread (coalesced)
  {
    const float* hs = H + (size_t)g * 16;
    float4 h0 = *(const float4*)hs, h1 = *(const float4*)(hs + 4);
    float4 h2 = *(const float4*)(hs + 8), h3 = *(const float4*)(hs + 12);
    *(short8*)(Hbf + (size_t)g * 16) = pack8(h0, h1);
    *(short8*)(Hbf + (size_t)g * 16 + 8) = pack8(h2, h3);
  }
  // adapters -> bf16 (grid-stride over short8 chunks)
#pragma unroll
  for (int j = 0; j < 3; ++j) {
    int c = g + j * 65536;
    if (c < ACH) {
      const float* su = Aup + (size_t)c * 8;
      const float* sg = Agate + (size_t)c * 8;
      float4 u0 = *(const float4*)su, u1 = *(const float4*)(su + 4);
      float4 g0 = *(const float4*)sg, g1 = *(const float4*)(sg + 4);
      *(short8*)(Aubf + (size_t)c * 8) = pack8(u0, u1);
      *(short8*)(Agbf + (size_t)c * 8) = pack8(g0, g1);
    }
  }

  __shared__ float alpha[2][E][M];
  if (t < 16) {
    int mat = t >> 3, e = t & 7;
    const float* lg = (mat ? gate_logits : up_logits) + e * M;
    float v[M], mx = -1e30f, s = 0.f;
#pragma unroll
    for (int m = 0; m < M; ++m) { v[m] = lg[m]; mx = fmaxf(mx, v[m]); }
#pragma unroll
    for (int m = 0; m < M; ++m) { v[m] = expf(v[m] - mx); s += v[m]; }
#pragma unroll
    for (int m = 0; m < M; ++m) alpha[mat][e][m] = v[m] / s;
  }
  __syncthreads();
  int d = g >> 6, r = g & 63;
  float au[E] = {0, 0, 0, 0, 0, 0, 0, 0}, ag[E] = {0, 0, 0, 0, 0, 0, 0, 0};
#pragma unroll
  for (int m = 0; m < M; ++m) {
    float vu = up_bank[((size_t)m * D + d) * R + r];
    float vg = gate_bank[((size_t)m * D + d) * R + r];
#pragma unroll
    for (int e = 0; e < E; ++e) {
      au[e] += alpha[0][e][m] * vu;
      ag[e] += alpha[1][e][m] * vg;
    }
  }
#pragma unroll
  for (int e = 0; e < E; ++e) {
    mxT[((size_t)e * 128 + r) * D + d] = f2bf(au[e]);
    mxT[((size_t)e * 128 + 64 + r) * D + d] = f2bf(ag[e]);
  }
}

// ---------------------------------------------------------------------------
// K2: t[pos, n] = H[tok, :] @ mixed^T  (n = 0..63 up, 64..127 gate)
// FULL-K (16 iters over D=1024), f32 register accumulate, ONE bf16 store.
// No LDS, no barriers, no atomics. grid (E, 16 tiles of 64 tok), block = 4
// independent waves of 16 tok x 128 n. mxT[e] = 256 KB -> L2-resident.
// gridDim.x == 8 -> expert-e blocks pinned to XCD e.
// ---------------------------------------------------------------------------
__global__ __launch_bounds__(256) void k_t(
    const unsigned short* __restrict__ Hbf, const unsigned short* __restrict__ mxT,
    const int* __restrict__ perm, const int* __restrict__ offs,
    unsigned short* __restrict__ tbuf) {
  int e = blockIdx.x;
  int end = offs[e + 1];
  int t = threadIdx.x, lane = t & 63, w = t >> 6;
  int quad = lane >> 4, l15 = lane & 15;
  int row0 = offs[e] + blockIdx.y * 64 + w * 16;
  if (row0 >= end) return;  // wave-uniform exit
  int pos = row0 + l15;
  int tok = (pos < end) ? perm[pos] : -1;
  const unsigned short* hrow = Hbf + (size_t)(tok < 0 ? 0 : tok) * D;
  const unsigned short* brow = mxT + (size_t)e * 128 * D;
  floatx4 acc[8];
#pragma unroll
  for (int nt = 0; nt < 8; ++nt) acc[nt] = (floatx4){0.f, 0.f, 0.f, 0.f};
  for (int kt = 0; kt < 16; ++kt) {
#pragma unroll
    for (int ks = 0; ks < 2; ++ks) {
      int kc = kt * 64 + ks * 32 + quad * 8;
      short8 a = (short8){0, 0, 0, 0, 0, 0, 0, 0};
      if (tok >= 0) a = *(const short8*)(hrow + kc);
#pragma unroll
      for (int nt = 0; nt < 8; ++nt) {
        short8 bb = *(const short8*)(brow + (size_t)(nt * 16 + l15) * D + kc);
        acc[nt] = __builtin_amdgcn_mfma_f32_16x16x32_bf16(a, bb, acc[nt], 0, 0, 0);
      }
    }
  }
#pragma unroll
  for (int reg = 0; reg < 4; ++reg) {
    int p = row0 + quad * 4 + reg;
    if (p < end) {
#pragma unroll
      for (int nt = 0; nt < 8; ++nt)
        tbuf[(size_t)p * 128 + nt * 16 + l15] = f2bf(acc[nt][reg]);
    }
  }
}

// ---------------------------------------------------------------------------
// K3: inter[pos, p] = silu(t_g @ Ag[p]) * (t_u @ Au[p]), bf16 out.
// No LDS, no barriers, direct stores. grid (E, 64 tok-tiles of 16, P/256=11),
// block = 4 indep waves of 16 tok x 64 p. A-frags: bf16 tbuf short8 direct;
// B-frags: bf16 adapters (L2-resident per XCD).
// ---------------------------------------------------------------------------
__global__ __launch_bounds__(256) void k_inter(
    const unsigned short* __restrict__ tbuf, const unsigned short* __restrict__ Aubf,
    const unsigned short* __restrict__ Agbf, const int* __restrict__ offs,
    unsigned short* __restrict__ inter) {
  int e = blockIdx.x;
  int start = offs[e] + blockIdx.y * 16;
  int end = offs[e + 1];
  if (start >= end) return;
  int t = threadIdx.x, lane = t & 63, w = t >> 6;
  int quad = lane >> 4, l15 = lane & 15;
  int p0 = blockIdx.z * 256 + w * 64;
  int pos = start + l15;
  bool okA = pos < end;
  floatx4 accu[4], accg[4];
#pragma unroll
  for (int nt = 0; nt < 4; ++nt) {
    accu[nt] = (floatx4){0.f, 0.f, 0.f, 0.f};
    accg[nt] = (floatx4){0.f, 0.f, 0.f, 0.f};
  }
#pragma unroll
  for (int ks = 0; ks < 2; ++ks) {
    int kc = ks * 32 + quad * 8;
    short8 au = (short8){0, 0, 0, 0, 0, 0, 0, 0};
    short8 ag = (short8){0, 0, 0, 0, 0, 0, 0, 0};
    if (okA) {
      au = *(const short8*)(tbuf + (size_t)pos * 128 + kc);
      ag = *(const short8*)(tbuf + (size_t)pos * 128 + 64 + kc);
    }
#pragma unroll
    for (int nt = 0; nt < 4; ++nt) {
      size_t prow = (size_t)e * P + p0 + nt * 16 + l15;
      short8 bu = *(const short8*)(Aubf + prow * R + kc);
      short8 bg = *(const short8*)(Agbf + prow * R + kc);
      accu[nt] = __builtin_amdgcn_mfma_f32_16x16x32_bf16(au, bu, accu[nt], 0, 0, 0);
      accg[nt] = __builtin_amdgcn_mfma_f32_16x16x32_bf16(ag, bg, accg[nt], 0, 0, 0);
    }
  }
#pragma unroll
  for (int nt = 0; nt < 4; ++nt)
#pragma unroll
    for (int reg = 0; reg < 4; ++reg) {
      int prow = start + quad * 4 + reg;
      if (prow < end) {
        float gv = accg[nt][reg], uv = accu[nt][reg];
        float val = uv * (gv / (1.f + __expf(-gv)));
        inter[(size_t)prow * P + p0 + nt * 16 + l15] = f2bf(val);
      }
    }
}

// ---------------------------------------------------------------------------
// K4: out[tok, d] = wts[tok] * (inter[tok,:] @ Wd[e,d,:]^T). FULL-K: 44 iters
// of BK=64 -> NO atomics (K=1 routing: out rows disjoint across experts),
// direct stores, no output zeroing. 128-tok y-tiles (~= tokens/expert) so Wd
// is read ~once. grid (E, 8, 16 d-tiles of 64): active ~130-190 blocks, all
// expert-e blocks on XCD e (linear%8==e) -> Wd slice shared via XCD L2.
// Register-prefetched LDS loop (proven round-0 codegen pattern).
// ---------------------------------------------------------------------------
__global__ __launch_bounds__(256) void k_down(
    const unsigned short* __restrict__ inter, const float* __restrict__ Wd,
    const int* __restrict__ perm, const int* __restrict__ offs,
    const float* __restrict__ wts, float* __restrict__ out) {
  int e = blockIdx.x;
  int start = offs[e] + blockIdx.y * 128;
  int end = offs[e + 1];
  if (start >= end) return;
  int d0 = blockIdx.z * 64;
  __shared__ unsigned short As[128][72];  // 18.4 KB
  __shared__ unsigned short Bs[64][72];   //  9.2 KB
  int t = threadIdx.x;
  int lane = t & 63, w = t >> 6, quad = lane >> 4, l15 = lane & 15;

  // A staging: row t>>1 (128 rows), 64B/thread (4 short8 at cols (t&1)*32).
  int arow = t >> 1;
  int apos = start + arow;
  bool aok = apos < end;
  const unsigned short* aptr =
      inter + (size_t)(aok ? apos : start) * P + (t & 1) * 32;
  // B staging: row t>>2 (64 d-rows), 64B/thread (4 float4 at cols (t&3)*16).
  const float* bptr = Wd + ((size_t)(e * D + d0 + (t >> 2)) * P + (t & 3) * 16);

  short8 pa[4];
  float4 pb[4];
#pragma unroll
  for (int q = 0; q < 4; ++q)
    pa[q] = aok ? *(const short8*)(aptr + q * 8) : (short8){0, 0, 0, 0, 0, 0, 0, 0};
#pragma unroll
  for (int q = 0; q < 4; ++q) pb[q] = *(const float4*)(bptr + q * 4);

  floatx4 acc[2][4];
#pragma unroll
  for (int tt = 0; tt < 2; ++tt)
#pragma unroll
    for (int dt = 0; dt < 4; ++dt) acc[tt][dt] = (floatx4){0.f, 0.f, 0.f, 0.f};

  for (int it = 0; it < NITD; ++it) {
#pragma unroll
    for (int q = 0; q < 4; ++q)
      *(short8*)&As[arow][(t & 1) * 32 + q * 8] = pa[q];
    *(short8*)&Bs[t >> 2][(t & 3) * 16] = pack8(pb[0], pb[1]);
    *(short8*)&Bs[t >> 2][(t & 3) * 16 + 8] = pack8(pb[2], pb[3]);
    __syncthreads();
    if (it + 1 < NITD) {  // prefetch next tile (overlaps MFMA below)
      int k0 = (it + 1) * 64;
#pragma unroll
      for (int q = 0; q < 4; ++q)
        pa[q] = aok ? *(const short8*)(aptr + k0 + q * 8) : (short8){0, 0, 0, 0, 0, 0, 0, 0};
#pragma unroll
      for (int q = 0; q < 4; ++q) pb[q] = *(const float4*)(bptr + k0 + q * 4);
    }
#pragma unroll
    for (int ks = 0; ks < 2; ++ks) {
      int kc = ks * 32 + quad * 8;
      short8 a[2], b[4];
#pragma unroll
      for (int tt = 0; tt < 2; ++tt) a[tt] = *(const short8*)&As[w * 32 + tt * 16 + l15][kc];
#pragma unroll
      for (int dt = 0; dt < 4; ++dt) b[dt] = *(const short8*)&Bs[dt * 16 + l15][kc];
#pragma unroll
      for (int tt = 0; tt < 2; ++tt)
#pragma unroll
        for (int dt = 0; dt < 4; ++dt)
          acc[tt][dt] = __builtin_amdgcn_mfma_f32_16x16x32_bf16(a[tt], b[dt], acc[tt][dt], 0, 0, 0);
    }
    __syncthreads();
  }
#pragma unroll
  for (int tt = 0; tt < 2; ++tt)
#pragma unroll
    for (int reg = 0; reg < 4; ++reg) {
      int pos = start + w * 32 + tt * 16 + quad * 4 + reg;
      if (pos < end) {
        int tok = perm[pos];
        float wt = wts[tok];
#pragma unroll
        for (int dt = 0; dt < 4; ++dt)
          out[(size_t)tok * D + d0 + dt * 16 + l15] = acc[tt][dt][reg] * wt;
      }
    }
}

// ---------------------------------------------------------------------------
extern "C" void kernel_launch(void* const* d_in, const int* in_sizes, int n_in,
                              void* d_out, int out_size, void* d_ws, size_t ws_size,
                              hipStream_t stream) {
  const float* H = (const float*)d_in[0];
  const int* idx = (const int*)d_in[1];
  const float* wts = (const float*)d_in[2];
  const float* Aup = (const float*)d_in[3];
  const float* Agate = (const float*)d_in[4];
  const float* upl = (const float*)d_in[5];
  const float* gatel = (const float*)d_in[6];
  const float* Wd = (const float*)d_in[7];
  const float* upb = (const float*)d_in[8];
  const float* gateb = (const float*)d_in[9];
  float* out = (float*)d_out;

  char* ws = (char*)d_ws;
  unsigned short* Hbf = (unsigned short*)ws;                  // S*D bf16 = 2 MB
  unsigned short* mxT = Hbf + (size_t)S * D;                  // E*128*D bf16 = 2 MB
  unsigned short* Aubf = mxT + (size_t)E * 128 * D;           // E*P*R bf16 = 2.9 MB
  unsigned short* Agbf = Aubf + (size_t)E * P * R;            // 2.9 MB
  unsigned short* inter = Agbf + (size_t)E * P * R;           // S*P bf16 = 5.8 MB
  unsigned short* tbuf = inter + (size_t)S * P;               // S*128 bf16 = 256 KB
  int* perm = (int*)(tbuf + (size_t)S * 128);
  int* offs = perm + S;

  k_pre<<<256, 256, 0, stream>>>(upl, gatel, upb, gateb, H, Aup, Agate, idx,
                                 Hbf, mxT, Aubf, Agbf, perm, offs);
  k_t<<<dim3(E, 16), 256, 0, stream>>>(Hbf, mxT, perm, offs, tbuf);
  k_inter<<<dim3(E, 64, P / 256), 256, 0, stream>>>(tbuf, Aubf, Agbf, offs, inter);
  k_down<<<dim3(E, 8, 16), 256, 0, stream>>>(inter, Wd, perm, offs, wts, out);
}

// Round 3
// 225.588 us; speedup vs baseline: 1.7559x; 1.7559x over previous
//
#include <hip/hip_runtime.h>
#include <hip/hip_bf16.h>
#include <math.h>

#define S 1024
#define D 1024
#define P 2816
#define R 64
#define E 8
#define M 16
#define KSPLIT 4
#define KQ (P / KSPLIT)        // 704
#define NIT (KQ / 64)          // 11
#define ZT 8                   // k_t K-split; slice = D/ZT = 128
#define ACH ((E * P * R) / 8)  // 180224 adapter short8-chunks

typedef __attribute__((ext_vector_type(8))) short short8;   // 8 bf16 (4 VGPRs)
typedef __attribute__((ext_vector_type(4))) float floatx4;  // MFMA acc

static __device__ inline unsigned short f2bf(float f) {
  __hip_bfloat16 h = __float2bfloat16(f);
  return *reinterpret_cast<unsigned short*>(&h);
}
static __device__ inline short8 pack8(float4 a, float4 b) {
  short8 v;
  v[0] = f2bf(a.x); v[1] = f2bf(a.y); v[2] = f2bf(a.z); v[3] = f2bf(a.w);
  v[4] = f2bf(b.x); v[5] = f2bf(b.y); v[6] = f2bf(b.z); v[7] = f2bf(b.w);
  return v;
}

// ---------------------------------------------------------------------------
// K1 (fused pre-pass), grid 256 x 256:
//  - zero out (k_down accumulates with atomics)
//  - counting sort (block 0)
//  - softmax alphas + mixed bases, TRANSPOSED: mxT[e][n=r|64+r][d] bf16
//  - H -> bf16 (Hbf), adapters -> bf16 (Aubf/Agbf)
// ---------------------------------------------------------------------------
__global__ __launch_bounds__(256) void k_pre(
    const float* __restrict__ up_logits, const float* __restrict__ gate_logits,
    const float* __restrict__ up_bank, const float* __restrict__ gate_bank,
    const float* __restrict__ H, const float* __restrict__ Aup,
    const float* __restrict__ Agate, const int* __restrict__ idx,
    unsigned short* __restrict__ Hbf, unsigned short* __restrict__ mxT,
    unsigned short* __restrict__ Aubf, unsigned short* __restrict__ Agbf,
    int* __restrict__ perm, int* __restrict__ offs, float* __restrict__ out) {
  int b = blockIdx.x, t = threadIdx.x;
  int g = b * 256 + t;
  // zero the output (k_down accumulates with atomics)
  float4 z4 = make_float4(0.f, 0.f, 0.f, 0.f);
#pragma unroll
  for (int j = 0; j < 4; ++j)
    *(float4*)(out + (size_t)b * 4096 + j * 1024 + t * 4) = z4;

  if (b == 0) {  // counting sort, 4 tokens/thread
    __shared__ int hist[E];
    __shared__ int basearr[E];
    if (t < E) hist[t] = 0;
    __syncthreads();
    int e4[4];
#pragma unroll
    for (int j = 0; j < 4; ++j) {
      e4[j] = idx[t + j * 256];
      atomicAdd(&hist[e4[j]], 1);
    }
    __syncthreads();
    if (t == 0) {
      int run = 0;
      for (int i = 0; i < E; ++i) { basearr[i] = run; offs[i] = run; run += hist[i]; }
      offs[E] = S;
    }
    __syncthreads();
#pragma unroll
    for (int j = 0; j < 4; ++j) {
      int pos = atomicAdd(&basearr[e4[j]], 1);
      perm[pos] = t + j * 256;
    }
  }

  // H -> bf16, 16 elems/thread (coalesced)
  {
    const float* hs = H + (size_t)g * 16;
    float4 h0 = *(const float4*)hs, h1 = *(const float4*)(hs + 4);
    float4 h2 = *(const float4*)(hs + 8), h3 = *(const float4*)(hs + 12);
    *(short8*)(Hbf + (size_t)g * 16) = pack8(h0, h1);
    *(short8*)(Hbf + (size_t)g * 16 + 8) = pack8(h2, h3);
  }
  // adapters -> bf16 (grid-stride over short8 chunks)
#pragma unroll
  for (int j = 0; j < 3; ++j) {
    int c = g + j * 65536;
    if (c < ACH) {
      const float* su = Aup + (size_t)c * 8;
      const float* sg = Agate + (size_t)c * 8;
      float4 u0 = *(const float4*)su, u1 = *(const float4*)(su + 4);
      float4 g0 = *(const float4*)sg, g1 = *(const float4*)(sg + 4);
      *(short8*)(Aubf + (size_t)c * 8) = pack8(u0, u1);
      *(short8*)(Agbf + (size_t)c * 8) = pack8(g0, g1);
    }
  }

  __shared__ float alpha[2][E][M];
  if (t < 16) {
    int mat = t >> 3, e = t & 7;
    const float* lg = (mat ? gate_logits : up_logits) + e * M;
    float v[M], mx = -1e30f, s = 0.f;
#pragma unroll
    for (int m = 0; m < M; ++m) { v[m] = lg[m]; mx = fmaxf(mx, v[m]); }
#pragma unroll
    for (int m = 0; m < M; ++m) { v[m] = expf(v[m] - mx); s += v[m]; }
#pragma unroll
    for (int m = 0; m < M; ++m) alpha[mat][e][m] = v[m] / s;
  }
  __syncthreads();
  int d = g >> 6, r = g & 63;
  float au[E] = {0, 0, 0, 0, 0, 0, 0, 0}, ag[E] = {0, 0, 0, 0, 0, 0, 0, 0};
#pragma unroll
  for (int m = 0; m < M; ++m) {
    float vu = up_bank[((size_t)m * D + d) * R + r];
    float vg = gate_bank[((size_t)m * D + d) * R + r];
#pragma unroll
    for (int e = 0; e < E; ++e) {
      au[e] += alpha[0][e][m] * vu;
      ag[e] += alpha[1][e][m] * vg;
    }
  }
#pragma unroll
  for (int e = 0; e < E; ++e) {
    mxT[((size_t)e * 128 + r) * D + d] = f2bf(au[e]);
    mxT[((size_t)e * 128 + 64 + r) * D + d] = f2bf(ag[e]);
  }
}

// ---------------------------------------------------------------------------
// K2: t-partials. ONE WAVE per block (64 threads): 16 tok x 128 n x K=128.
// grid (E, 16 tok-tiles of 16, ZT=8 K-slices) = 1024 blocks, ~512 active
// waves (2/SIMD-group) -- fixes round-2's 64-active-wave starvation.
// No LDS, no barriers, no atomics: f32 partials tpart[z][pos][n].
// ---------------------------------------------------------------------------
__global__ __launch_bounds__(64) void k_t(
    const unsigned short* __restrict__ Hbf, const unsigned short* __restrict__ mxT,
    const int* __restrict__ perm, const int* __restrict__ offs,
    float* __restrict__ tpart) {
  int e = blockIdx.x;
  int end = offs[e + 1];
  int row0 = offs[e] + blockIdx.y * 16;
  if (row0 >= end) return;
  int lane = threadIdx.x & 63;
  int quad = lane >> 4, l15 = lane & 15;
  int z = blockIdx.z;
  int k0 = z * (D / ZT);
  int pos = row0 + l15;
  int tok = (pos < end) ? perm[pos] : -1;
  const unsigned short* hrow = Hbf + (size_t)(tok < 0 ? 0 : tok) * D + k0;
  const unsigned short* brow = mxT + (size_t)e * 128 * D + k0;
  floatx4 acc[8];
#pragma unroll
  for (int nt = 0; nt < 8; ++nt) acc[nt] = (floatx4){0.f, 0.f, 0.f, 0.f};
#pragma unroll
  for (int ks = 0; ks < 4; ++ks) {  // K = 128 = 4 x 32
    int kc = ks * 32 + quad * 8;
    short8 a = (short8){0, 0, 0, 0, 0, 0, 0, 0};
    if (tok >= 0) a = *(const short8*)(hrow + kc);
#pragma unroll
    for (int nt = 0; nt < 8; ++nt) {
      short8 bb = *(const short8*)(brow + (size_t)(nt * 16 + l15) * D + kc);
      acc[nt] = __builtin_amdgcn_mfma_f32_16x16x32_bf16(a, bb, acc[nt], 0, 0, 0);
    }
  }
#pragma unroll
  for (int reg = 0; reg < 4; ++reg) {
    int p = row0 + quad * 4 + reg;
    if (p < end) {
#pragma unroll
      for (int nt = 0; nt < 8; ++nt)
        tpart[((size_t)z * S + p) * 128 + nt * 16 + l15] = acc[nt][reg];
    }
  }
}

// K2b: reduce ZT partials -> tbuf bf16. grid 256 x 256, 2 elems/thread (~2 us).
__global__ __launch_bounds__(256) void k_tred(
    const float* __restrict__ tpart, unsigned short* __restrict__ tbuf) {
  int i = (blockIdx.x * 256 + threadIdx.x) * 2;
  float2 s = make_float2(0.f, 0.f);
#pragma unroll
  for (int z = 0; z < ZT; ++z) {
    float2 v = *(const float2*)(tpart + (size_t)z * S * 128 + i);
    s.x += v.x; s.y += v.y;
  }
  unsigned int pk = (unsigned int)f2bf(s.x) | ((unsigned int)f2bf(s.y) << 16);
  *(unsigned int*)(tbuf + i) = pk;
}

// ---------------------------------------------------------------------------
// K3: inter[pos, p] = silu(t_g @ Ag[p]) * (t_u @ Au[p]), bf16 out.
// No LDS, no barriers, direct stores. grid (E, 16 tok-tiles of 16, P/256=11),
// block = 4 indep waves of 16 tok x 64 p. A-frags: bf16 tbuf short8 direct;
// B-frags: bf16 adapters (L2-resident per XCD).
// ---------------------------------------------------------------------------
__global__ __launch_bounds__(256) void k_inter(
    const unsigned short* __restrict__ tbuf, const unsigned short* __restrict__ Aubf,
    const unsigned short* __restrict__ Agbf, const int* __restrict__ offs,
    unsigned short* __restrict__ inter) {
  int e = blockIdx.x;
  int start = offs[e] + blockIdx.y * 16;
  int end = offs[e + 1];
  if (start >= end) return;
  int t = threadIdx.x, lane = t & 63, w = t >> 6;
  int quad = lane >> 4, l15 = lane & 15;
  int p0 = blockIdx.z * 256 + w * 64;
  int pos = start + l15;
  bool okA = pos < end;
  floatx4 accu[4], accg[4];
#pragma unroll
  for (int nt = 0; nt < 4; ++nt) {
    accu[nt] = (floatx4){0.f, 0.f, 0.f, 0.f};
    accg[nt] = (floatx4){0.f, 0.f, 0.f, 0.f};
  }
#pragma unroll
  for (int ks = 0; ks < 2; ++ks) {
    int kc = ks * 32 + quad * 8;
    short8 au = (short8){0, 0, 0, 0, 0, 0, 0, 0};
    short8 ag = (short8){0, 0, 0, 0, 0, 0, 0, 0};
    if (okA) {
      au = *(const short8*)(tbuf + (size_t)pos * 128 + kc);
      ag = *(const short8*)(tbuf + (size_t)pos * 128 + 64 + kc);
    }
#pragma unroll
    for (int nt = 0; nt < 4; ++nt) {
      size_t prow = (size_t)e * P + p0 + nt * 16 + l15;
      short8 bu = *(const short8*)(Aubf + prow * R + kc);
      short8 bg = *(const short8*)(Agbf + prow * R + kc);
      accu[nt] = __builtin_amdgcn_mfma_f32_16x16x32_bf16(au, bu, accu[nt], 0, 0, 0);
      accg[nt] = __builtin_amdgcn_mfma_f32_16x16x32_bf16(ag, bg, accg[nt], 0, 0, 0);
    }
  }
#pragma unroll
  for (int nt = 0; nt < 4; ++nt)
#pragma unroll
    for (int reg = 0; reg < 4; ++reg) {
      int prow = start + quad * 4 + reg;
      if (prow < end) {
        float gv = accg[nt][reg], uv = accu[nt][reg];
        float val = uv * (gv / (1.f + __expf(-gv)));
        inter[(size_t)prow * P + p0 + nt * 16 + l15] = f2bf(val);
      }
    }
}

// ---------------------------------------------------------------------------
// K4: out[tok, d] += wts[tok] * (inter @ Wd^T) -- ROUND-0 VERBATIM (55.7 us,
// the measured optimum of the 3 tried configs: 256-tok tile keeps 32
// MFMA/wave/iter per barrier round; KSPLIT=4 gives 512 blocks = 2/CU).
// grid (E, KSPLIT=4, D/64=16), block 256. Tile 256 tok x 64 d, BK=64.
// ---------------------------------------------------------------------------
__global__ __launch_bounds__(256) void k_down(
    const unsigned short* __restrict__ inter, const float* __restrict__ Wd,
    const int* __restrict__ perm, const int* __restrict__ offs,
    const float* __restrict__ wts, float* __restrict__ out) {
  int e = blockIdx.x;
  int start = offs[e];
  int end = offs[e + 1];
  if (start >= end) return;
  int kz = blockIdx.y;
  int d0 = blockIdx.z * 64;
  __shared__ unsigned short As[256][72];  // 36.9 KB
  __shared__ unsigned short Bs[64][72];   //  9.2 KB
  int t = threadIdx.x;
  int lane = t & 63, w = t >> 6, quad = lane >> 4, l15 = lane & 15;

  // A staging: 8 chunks/thread; fixed col (t&7)*8, rows (t>>3)+32j
  const unsigned short* aptr[8];
  bool aok[8];
#pragma unroll
  for (int j = 0; j < 8; ++j) {
    int arow = (t >> 3) + 32 * j;
    int pos = start + arow;
    aok[j] = (pos < end);
    aptr[j] = inter + (size_t)(aok[j] ? pos : start) * P + kz * KQ + (t & 7) * 8;
  }
  // B staging: row t>>2, cols (t&3)*16 .. +16 (fp32)
  const float* bsrc = Wd + ((size_t)(e * D + d0 + (t >> 2)) * P + kz * KQ + (t & 3) * 16);

  float4 pa[8];
  float4 pb[4];
#pragma unroll
  for (int j = 0; j < 8; ++j)
    pa[j] = aok[j] ? *(const float4*)(aptr[j]) : make_float4(0.f, 0.f, 0.f, 0.f);
#pragma unroll
  for (int q = 0; q < 4; ++q) pb[q] = *(const float4*)(bsrc + q * 4);

  floatx4 acc[4][4];
#pragma unroll
  for (int tt = 0; tt < 4; ++tt)
#pragma unroll
    for (int dt = 0; dt < 4; ++dt) acc[tt][dt] = (floatx4){0.f, 0.f, 0.f, 0.f};

  for (int it = 0; it < NIT; ++it) {
    // write staged registers to LDS (compiler inserts the vmcnt wait)
#pragma unroll
    for (int j = 0; j < 8; ++j)
      *(float4*)&As[(t >> 3) + 32 * j][(t & 7) * 8] = pa[j];
    {
      short8 bv0, bv1;
      bv0[0] = f2bf(pb[0].x); bv0[1] = f2bf(pb[0].y); bv0[2] = f2bf(pb[0].z); bv0[3] = f2bf(pb[0].w);
      bv0[4] = f2bf(pb[1].x); bv0[5] = f2bf(pb[1].y); bv0[6] = f2bf(pb[1].z); bv0[7] = f2bf(pb[1].w);
      bv1[0] = f2bf(pb[2].x); bv1[1] = f2bf(pb[2].y); bv1[2] = f2bf(pb[2].z); bv1[3] = f2bf(pb[2].w);
      bv1[4] = f2bf(pb[3].x); bv1[5] = f2bf(pb[3].y); bv1[6] = f2bf(pb[3].z); bv1[7] = f2bf(pb[3].w);
      *(short8*)&Bs[t >> 2][(t & 3) * 16] = bv0;
      *(short8*)&Bs[t >> 2][(t & 3) * 16 + 8] = bv1;
    }
    __syncthreads();
    // prefetch next iteration's tiles (overlaps with MFMA below)
    if (it + 1 < NIT) {
      int k0 = (it + 1) * 64;
#pragma unroll
      for (int j = 0; j < 8; ++j)
        pa[j] = aok[j] ? *(const float4*)(aptr[j] + k0) : make_float4(0.f, 0.f, 0.f, 0.f);
#pragma unroll
      for (int q = 0; q < 4; ++q) pb[q] = *(const float4*)(bsrc + k0 + q * 4);
    }
#pragma unroll
    for (int ks = 0; ks < 2; ++ks) {
      int kc = ks * 32 + quad * 8;
      short8 a[4], b[4];
#pragma unroll
      for (int tt = 0; tt < 4; ++tt) a[tt] = *(const short8*)&As[w * 64 + tt * 16 + l15][kc];
#pragma unroll
      for (int dt = 0; dt < 4; ++dt) b[dt] = *(const short8*)&Bs[dt * 16 + l15][kc];
#pragma unroll
      for (int tt = 0; tt < 4; ++tt)
#pragma unroll
        for (int dt = 0; dt < 4; ++dt)
          acc[tt][dt] = __builtin_amdgcn_mfma_f32_16x16x32_bf16(a[tt], b[dt], acc[tt][dt], 0, 0, 0);
    }
    __syncthreads();
  }
#pragma unroll
  for (int tt = 0; tt < 4; ++tt)
#pragma unroll
    for (int reg = 0; reg < 4; ++reg) {
      int pos = start + w * 64 + tt * 16 + quad * 4 + reg;
      if (pos < end) {
        int tok = perm[pos];
        float wt = wts[tok];
#pragma unroll
        for (int dt = 0; dt < 4; ++dt)
          atomicAdd(&out[(size_t)tok * D + d0 + dt * 16 + l15], acc[tt][dt][reg] * wt);
      }
    }
}

// ---------------------------------------------------------------------------
extern "C" void kernel_launch(void* const* d_in, const int* in_sizes, int n_in,
                              void* d_out, int out_size, void* d_ws, size_t ws_size,
                              hipStream_t stream) {
  const float* H = (const float*)d_in[0];
  const int* idx = (const int*)d_in[1];
  const float* wts = (const float*)d_in[2];
  const float* Aup = (const float*)d_in[3];
  const float* Agate = (const float*)d_in[4];
  const float* upl = (const float*)d_in[5];
  const float* gatel = (const float*)d_in[6];
  const float* Wd = (const float*)d_in[7];
  const float* upb = (const float*)d_in[8];
  const float* gateb = (const float*)d_in[9];
  float* out = (float*)d_out;

  char* ws = (char*)d_ws;
  unsigned short* Hbf = (unsigned short*)ws;                  // S*D bf16 = 2 MB
  unsigned short* mxT = Hbf + (size_t)S * D;                  // E*128*D bf16 = 2 MB
  unsigned short* Aubf = mxT + (size_t)E * 128 * D;           // E*P*R bf16 = 2.9 MB
  unsigned short* Agbf = Aubf + (size_t)E * P * R;            // 2.9 MB
  unsigned short* inter = Agbf + (size_t)E * P * R;           // S*P bf16 = 5.8 MB
  unsigned short* tbuf = inter + (size_t)S * P;               // S*128 bf16 = 256 KB
  float* tpart = (float*)(tbuf + (size_t)S * 128);            // ZT*S*128 f32 = 4 MB
  int* perm = (int*)(tpart + (size_t)ZT * S * 128);
  int* offs = perm + S;

  k_pre<<<256, 256, 0, stream>>>(upl, gatel, upb, gateb, H, Aup, Agate, idx,
                                 Hbf, mxT, Aubf, Agbf, perm, offs, out);
  k_t<<<dim3(E, 16, ZT), 64, 0, stream>>>(Hbf, mxT, perm, offs, tpart);
  k_tred<<<256, 256, 0, stream>>>(tpart, tbuf);
  k_inter<<<dim3(E, 16, P / 256), 256, 0, stream>>>(tbuf, Aubf, Agbf, offs, inter);
  k_down<<<dim3(E, KSPLIT, D / 64), 256, 0, stream>>>(inter, Wd, perm, offs, wts, out);
}

// Round 4
// 217.625 us; speedup vs baseline: 1.8202x; 1.0366x over previous
//
#include <hip/hip_runtime.h>
#include <hip/hip_bf16.h>
#include <math.h>

#define S 1024
#define D 1024
#define P 2816
#define R 64
#define E 8
#define M 16
#define KSPLIT 4
#define KQ (P / KSPLIT)        // 704
#define NIT (KQ / 64)          // 11
#define ZT 8                   // k_t K-split; slice = D/ZT = 128
#define ACH ((E * P * R) / 8)  // 180224 adapter short8-chunks

typedef __attribute__((ext_vector_type(8))) short short8;   // 8 bf16 (4 VGPRs)
typedef __attribute__((ext_vector_type(4))) float floatx4;  // MFMA acc

static __device__ inline unsigned short f2bf(float f) {
  __hip_bfloat16 h = __float2bfloat16(f);
  return *reinterpret_cast<unsigned short*>(&h);
}
static __device__ inline short8 pack8(float4 a, float4 b) {
  short8 v;
  v[0] = f2bf(a.x); v[1] = f2bf(a.y); v[2] = f2bf(a.z); v[3] = f2bf(a.w);
  v[4] = f2bf(b.x); v[5] = f2bf(b.y); v[6] = f2bf(b.z); v[7] = f2bf(b.w);
  return v;
}

// ---------------------------------------------------------------------------
// K1 (fused pre-pass), grid 256 x 256:
//  - counting sort (block 0)
//  - softmax alphas + mixed bases, TRANSPOSED: mxT[e][n=r|64+r][d] bf16
//  - H -> bf16 (Hbf), adapters -> bf16 (Aubf/Agbf)
// No out-zeroing anymore: k_red writes every out element exactly once.
// ---------------------------------------------------------------------------
__global__ __launch_bounds__(256) void k_pre(
    const float* __restrict__ up_logits, const float* __restrict__ gate_logits,
    const float* __restrict__ up_bank, const float* __restrict__ gate_bank,
    const float* __restrict__ H, const float* __restrict__ Aup,
    const float* __restrict__ Agate, const int* __restrict__ idx,
    unsigned short* __restrict__ Hbf, unsigned short* __restrict__ mxT,
    unsigned short* __restrict__ Aubf, unsigned short* __restrict__ Agbf,
    int* __restrict__ perm, int* __restrict__ offs) {
  int b = blockIdx.x, t = threadIdx.x;
  int g = b * 256 + t;

  if (b == 0) {  // counting sort, 4 tokens/thread
    __shared__ int hist[E];
    __shared__ int basearr[E];
    if (t < E) hist[t] = 0;
    __syncthreads();
    int e4[4];
#pragma unroll
    for (int j = 0; j < 4; ++j) {
      e4[j] = idx[t + j * 256];
      atomicAdd(&hist[e4[j]], 1);
    }
    __syncthreads();
    if (t == 0) {
      int run = 0;
      for (int i = 0; i < E; ++i) { basearr[i] = run; offs[i] = run; run += hist[i]; }
      offs[E] = S;
    }
    __syncthreads();
#pragma unroll
    for (int j = 0; j < 4; ++j) {
      int pos = atomicAdd(&basearr[e4[j]], 1);
      perm[pos] = t + j * 256;
    }
  }

  // H -> bf16, 16 elems/thread (coalesced)
  {
    const float* hs = H + (size_t)g * 16;
    float4 h0 = *(const float4*)hs, h1 = *(const float4*)(hs + 4);
    float4 h2 = *(const float4*)(hs + 8), h3 = *(const float4*)(hs + 12);
    *(short8*)(Hbf + (size_t)g * 16) = pack8(h0, h1);
    *(short8*)(Hbf + (size_t)g * 16 + 8) = pack8(h2, h3);
  }
  // adapters -> bf16 (grid-stride over short8 chunks)
#pragma unroll
  for (int j = 0; j < 3; ++j) {
    int c = g + j * 65536;
    if (c < ACH) {
      const float* su = Aup + (size_t)c * 8;
      const float* sg = Agate + (size_t)c * 8;
      float4 u0 = *(const float4*)su, u1 = *(const float4*)(su + 4);
      float4 g0 = *(const float4*)sg, g1 = *(const float4*)(sg + 4);
      *(short8*)(Aubf + (size_t)c * 8) = pack8(u0, u1);
      *(short8*)(Agbf + (size_t)c * 8) = pack8(g0, g1);
    }
  }

  __shared__ float alpha[2][E][M];
  if (t < 16) {
    int mat = t >> 3, e = t & 7;
    const float* lg = (mat ? gate_logits : up_logits) + e * M;
    float v[M], mx = -1e30f, s = 0.f;
#pragma unroll
    for (int m = 0; m < M; ++m) { v[m] = lg[m]; mx = fmaxf(mx, v[m]); }
#pragma unroll
    for (int m = 0; m < M; ++m) { v[m] = expf(v[m] - mx); s += v[m]; }
#pragma unroll
    for (int m = 0; m < M; ++m) alpha[mat][e][m] = v[m] / s;
  }
  __syncthreads();
  int d = g >> 6, r = g & 63;
  float au[E] = {0, 0, 0, 0, 0, 0, 0, 0}, ag[E] = {0, 0, 0, 0, 0, 0, 0, 0};
#pragma unroll
  for (int m = 0; m < M; ++m) {
    float vu = up_bank[((size_t)m * D + d) * R + r];
    float vg = gate_bank[((size_t)m * D + d) * R + r];
#pragma unroll
    for (int e = 0; e < E; ++e) {
      au[e] += alpha[0][e][m] * vu;
      ag[e] += alpha[1][e][m] * vg;
    }
  }
#pragma unroll
  for (int e = 0; e < E; ++e) {
    mxT[((size_t)e * 128 + r) * D + d] = f2bf(au[e]);
    mxT[((size_t)e * 128 + 64 + r) * D + d] = f2bf(ag[e]);
  }
}

// ---------------------------------------------------------------------------
// K2: t-partials. ONE WAVE per block (64 threads): 16 tok x 128 n x K=128.
// grid (E, 16 tok-tiles of 16, ZT=8 K-slices) = 1024 blocks.
// No LDS, no barriers, no atomics: f32 partials tpart[z][pos][n].
// ---------------------------------------------------------------------------
__global__ __launch_bounds__(64) void k_t(
    const unsigned short* __restrict__ Hbf, const unsigned short* __restrict__ mxT,
    const int* __restrict__ perm, const int* __restrict__ offs,
    float* __restrict__ tpart) {
  int e = blockIdx.x;
  int end = offs[e + 1];
  int row0 = offs[e] + blockIdx.y * 16;
  if (row0 >= end) return;
  int lane = threadIdx.x & 63;
  int quad = lane >> 4, l15 = lane & 15;
  int z = blockIdx.z;
  int k0 = z * (D / ZT);
  int pos = row0 + l15;
  int tok = (pos < end) ? perm[pos] : -1;
  const unsigned short* hrow = Hbf + (size_t)(tok < 0 ? 0 : tok) * D + k0;
  const unsigned short* brow = mxT + (size_t)e * 128 * D + k0;
  floatx4 acc[8];
#pragma unroll
  for (int nt = 0; nt < 8; ++nt) acc[nt] = (floatx4){0.f, 0.f, 0.f, 0.f};
#pragma unroll
  for (int ks = 0; ks < 4; ++ks) {  // K = 128 = 4 x 32
    int kc = ks * 32 + quad * 8;
    short8 a = (short8){0, 0, 0, 0, 0, 0, 0, 0};
    if (tok >= 0) a = *(const short8*)(hrow + kc);
#pragma unroll
    for (int nt = 0; nt < 8; ++nt) {
      short8 bb = *(const short8*)(brow + (size_t)(nt * 16 + l15) * D + kc);
      acc[nt] = __builtin_amdgcn_mfma_f32_16x16x32_bf16(a, bb, acc[nt], 0, 0, 0);
    }
  }
#pragma unroll
  for (int reg = 0; reg < 4; ++reg) {
    int p = row0 + quad * 4 + reg;
    if (p < end) {
#pragma unroll
      for (int nt = 0; nt < 8; ++nt)
        tpart[((size_t)z * S + p) * 128 + nt * 16 + l15] = acc[nt][reg];
    }
  }
}

// K2b: reduce ZT partials -> tbuf bf16. grid 256 x 256, 2 elems/thread.
__global__ __launch_bounds__(256) void k_tred(
    const float* __restrict__ tpart, unsigned short* __restrict__ tbuf) {
  int i = (blockIdx.x * 256 + threadIdx.x) * 2;
  float2 s = make_float2(0.f, 0.f);
#pragma unroll
  for (int z = 0; z < ZT; ++z) {
    float2 v = *(const float2*)(tpart + (size_t)z * S * 128 + i);
    s.x += v.x; s.y += v.y;
  }
  unsigned int pk = (unsigned int)f2bf(s.x) | ((unsigned int)f2bf(s.y) << 16);
  *(unsigned int*)(tbuf + i) = pk;
}

// ---------------------------------------------------------------------------
// K3: inter[pos, p] = silu(t_g @ Ag[p]) * (t_u @ Au[p]), bf16 out.
// No LDS, no barriers, direct stores. grid (E, 16 tok-tiles of 16, P/256=11),
// block = 4 indep waves of 16 tok x 64 p.
// ---------------------------------------------------------------------------
__global__ __launch_bounds__(256) void k_inter(
    const unsigned short* __restrict__ tbuf, const unsigned short* __restrict__ Aubf,
    const unsigned short* __restrict__ Agbf, const int* __restrict__ offs,
    unsigned short* __restrict__ inter) {
  int e = blockIdx.x;
  int start = offs[e] + blockIdx.y * 16;
  int end = offs[e + 1];
  if (start >= end) return;
  int t = threadIdx.x, lane = t & 63, w = t >> 6;
  int quad = lane >> 4, l15 = lane & 15;
  int p0 = blockIdx.z * 256 + w * 64;
  int pos = start + l15;
  bool okA = pos < end;
  floatx4 accu[4], accg[4];
#pragma unroll
  for (int nt = 0; nt < 4; ++nt) {
    accu[nt] = (floatx4){0.f, 0.f, 0.f, 0.f};
    accg[nt] = (floatx4){0.f, 0.f, 0.f, 0.f};
  }
#pragma unroll
  for (int ks = 0; ks < 2; ++ks) {
    int kc = ks * 32 + quad * 8;
    short8 au = (short8){0, 0, 0, 0, 0, 0, 0, 0};
    short8 ag = (short8){0, 0, 0, 0, 0, 0, 0, 0};
    if (okA) {
      au = *(const short8*)(tbuf + (size_t)pos * 128 + kc);
      ag = *(const short8*)(tbuf + (size_t)pos * 128 + 64 + kc);
    }
#pragma unroll
    for (int nt = 0; nt < 4; ++nt) {
      size_t prow = (size_t)e * P + p0 + nt * 16 + l15;
      short8 bu = *(const short8*)(Aubf + prow * R + kc);
      short8 bg = *(const short8*)(Agbf + prow * R + kc);
      accu[nt] = __builtin_amdgcn_mfma_f32_16x16x32_bf16(au, bu, accu[nt], 0, 0, 0);
      accg[nt] = __builtin_amdgcn_mfma_f32_16x16x32_bf16(ag, bg, accg[nt], 0, 0, 0);
    }
  }
#pragma unroll
  for (int nt = 0; nt < 4; ++nt)
#pragma unroll
    for (int reg = 0; reg < 4; ++reg) {
      int prow = start + quad * 4 + reg;
      if (prow < end) {
        float gv = accg[nt][reg], uv = accu[nt][reg];
        float val = uv * (gv / (1.f + __expf(-gv)));
        inter[(size_t)prow * P + p0 + nt * 16 + l15] = f2bf(val);
      }
    }
}

// ---------------------------------------------------------------------------
// K4: down-projection partials. IDENTICAL loop to the measured 54-us kernel;
// ONLY the epilogue changed: plain coalesced stores of K-split partials into
// pos-space dpart[kz][pos][d] (each pos owned by exactly one expert -> no
// overlap, no atomics, no out-zeroing). A/B test of the atomic-bound theory
// (WRITE_SIZE was exactly KSPLIT x out = 16 MB of RMW traffic; 8.4M atomics
// at ~64/cy ~= 55 us = the observed floor).
// grid (E, KSPLIT=4, D/64=16), block 256. Tile 256 tok x 64 d, BK=64.
// ---------------------------------------------------------------------------
__global__ __launch_bounds__(256) void k_down(
    const unsigned short* __restrict__ inter, const float* __restrict__ Wd,
    const int* __restrict__ offs, float* __restrict__ dpart) {
  int e = blockIdx.x;
  int start = offs[e];
  int end = offs[e + 1];
  if (start >= end) return;
  int kz = blockIdx.y;
  int d0 = blockIdx.z * 64;
  __shared__ unsigned short As[256][72];  // 36.9 KB
  __shared__ unsigned short Bs[64][72];   //  9.2 KB
  int t = threadIdx.x;
  int lane = t & 63, w = t >> 6, quad = lane >> 4, l15 = lane & 15;

  // A staging: 8 chunks/thread; fixed col (t&7)*8, rows (t>>3)+32j
  const unsigned short* aptr[8];
  bool aok[8];
#pragma unroll
  for (int j = 0; j < 8; ++j) {
    int arow = (t >> 3) + 32 * j;
    int pos = start + arow;
    aok[j] = (pos < end);
    aptr[j] = inter + (size_t)(aok[j] ? pos : start) * P + kz * KQ + (t & 7) * 8;
  }
  // B staging: row t>>2, cols (t&3)*16 .. +16 (fp32)
  const float* bsrc = Wd + ((size_t)(e * D + d0 + (t >> 2)) * P + kz * KQ + (t & 3) * 16);

  float4 pa[8];
  float4 pb[4];
#pragma unroll
  for (int j = 0; j < 8; ++j)
    pa[j] = aok[j] ? *(const float4*)(aptr[j]) : make_float4(0.f, 0.f, 0.f, 0.f);
#pragma unroll
  for (int q = 0; q < 4; ++q) pb[q] = *(const float4*)(bsrc + q * 4);

  floatx4 acc[4][4];
#pragma unroll
  for (int tt = 0; tt < 4; ++tt)
#pragma unroll
    for (int dt = 0; dt < 4; ++dt) acc[tt][dt] = (floatx4){0.f, 0.f, 0.f, 0.f};

  for (int it = 0; it < NIT; ++it) {
    // write staged registers to LDS (compiler inserts the vmcnt wait)
#pragma unroll
    for (int j = 0; j < 8; ++j)
      *(float4*)&As[(t >> 3) + 32 * j][(t & 7) * 8] = pa[j];
    {
      short8 bv0, bv1;
      bv0[0] = f2bf(pb[0].x); bv0[1] = f2bf(pb[0].y); bv0[2] = f2bf(pb[0].z); bv0[3] = f2bf(pb[0].w);
      bv0[4] = f2bf(pb[1].x); bv0[5] = f2bf(pb[1].y); bv0[6] = f2bf(pb[1].z); bv0[7] = f2bf(pb[1].w);
      bv1[0] = f2bf(pb[2].x); bv1[1] = f2bf(pb[2].y); bv1[2] = f2bf(pb[2].z); bv1[3] = f2bf(pb[2].w);
      bv1[4] = f2bf(pb[3].x); bv1[5] = f2bf(pb[3].y); bv1[6] = f2bf(pb[3].z); bv1[7] = f2bf(pb[3].w);
      *(short8*)&Bs[t >> 2][(t & 3) * 16] = bv0;
      *(short8*)&Bs[t >> 2][(t & 3) * 16 + 8] = bv1;
    }
    __syncthreads();
    // prefetch next iteration's tiles (overlaps with MFMA below)
    if (it + 1 < NIT) {
      int k0 = (it + 1) * 64;
#pragma unroll
      for (int j = 0; j < 8; ++j)
        pa[j] = aok[j] ? *(const float4*)(aptr[j] + k0) : make_float4(0.f, 0.f, 0.f, 0.f);
#pragma unroll
      for (int q = 0; q < 4; ++q) pb[q] = *(const float4*)(bsrc + k0 + q * 4);
    }
#pragma unroll
    for (int ks = 0; ks < 2; ++ks) {
      int kc = ks * 32 + quad * 8;
      short8 a[4], b[4];
#pragma unroll
      for (int tt = 0; tt < 4; ++tt) a[tt] = *(const short8*)&As[w * 64 + tt * 16 + l15][kc];
#pragma unroll
      for (int dt = 0; dt < 4; ++dt) b[dt] = *(const short8*)&Bs[dt * 16 + l15][kc];
#pragma unroll
      for (int tt = 0; tt < 4; ++tt)
#pragma unroll
        for (int dt = 0; dt < 4; ++dt)
          acc[tt][dt] = __builtin_amdgcn_mfma_f32_16x16x32_bf16(a[tt], b[dt], acc[tt][dt], 0, 0, 0);
    }
    __syncthreads();
  }
  float* dp = dpart + (size_t)kz * S * D;
#pragma unroll
  for (int tt = 0; tt < 4; ++tt)
#pragma unroll
    for (int reg = 0; reg < 4; ++reg) {
      int pos = start + w * 64 + tt * 16 + quad * 4 + reg;
      if (pos < end) {
#pragma unroll
        for (int dt = 0; dt < 4; ++dt)
          dp[(size_t)pos * D + d0 + dt * 16 + l15] = acc[tt][dt][reg];
      }
    }
}

// ---------------------------------------------------------------------------
// K5: out[perm[pos], d] = wts[perm[pos]] * sum_kz dpart[kz][pos][d].
// 16 MB read + 4 MB write, coalesced lanes over d; grid 256 x 256, 4 rows/blk.
// ---------------------------------------------------------------------------
__global__ __launch_bounds__(256) void k_red(
    const float* __restrict__ dpart, const int* __restrict__ perm,
    const float* __restrict__ wts, float* __restrict__ out) {
  int t = threadIdx.x;
  int row = blockIdx.x * 4 + (t >> 6);
  int lane = t & 63;
  int tok = perm[row];
  float wt = wts[tok];
  const float* src = dpart + (size_t)row * D + lane * 4;
  float* dst = out + (size_t)tok * D + lane * 4;
#pragma unroll
  for (int j = 0; j < 4; ++j) {
    float4 s = *(const float4*)(src + j * 256);
#pragma unroll
    for (int kz = 1; kz < KSPLIT; ++kz) {
      float4 v = *(const float4*)(src + (size_t)kz * S * D + j * 256);
      s.x += v.x; s.y += v.y; s.z += v.z; s.w += v.w;
    }
    s.x *= wt; s.y *= wt; s.z *= wt; s.w *= wt;
    *(float4*)(dst + j * 256) = s;
  }
}

// ---------------------------------------------------------------------------
extern "C" void kernel_launch(void* const* d_in, const int* in_sizes, int n_in,
                              void* d_out, int out_size, void* d_ws, size_t ws_size,
                              hipStream_t stream) {
  const float* H = (const float*)d_in[0];
  const int* idx = (const int*)d_in[1];
  const float* wts = (const float*)d_in[2];
  const float* Aup = (const float*)d_in[3];
  const float* Agate = (const float*)d_in[4];
  const float* upl = (const float*)d_in[5];
  const float* gatel = (const float*)d_in[6];
  const float* Wd = (const float*)d_in[7];
  const float* upb = (const float*)d_in[8];
  const float* gateb = (const float*)d_in[9];
  float* out = (float*)d_out;

  char* ws = (char*)d_ws;
  unsigned short* Hbf = (unsigned short*)ws;                  // S*D bf16 = 2 MB
  unsigned short* mxT = Hbf + (size_t)S * D;                  // E*128*D bf16 = 2 MB
  unsigned short* Aubf = mxT + (size_t)E * 128 * D;           // E*P*R bf16 = 2.9 MB
  unsigned short* Agbf = Aubf + (size_t)E * P * R;            // 2.9 MB
  unsigned short* inter = Agbf + (size_t)E * P * R;           // S*P bf16 = 5.8 MB
  unsigned short* tbuf = inter + (size_t)S * P;               // S*128 bf16 = 256 KB
  float* tpart = (float*)(tbuf + (size_t)S * 128);            // ZT*S*128 f32 = 4 MB
  float* dpart = tpart + (size_t)ZT * S * 128;                // KSPLIT*S*D f32 = 16 MB
  int* perm = (int*)(dpart + (size_t)KSPLIT * S * D);
  int* offs = perm + S;

  k_pre<<<256, 256, 0, stream>>>(upl, gatel, upb, gateb, H, Aup, Agate, idx,
                                 Hbf, mxT, Aubf, Agbf, perm, offs);
  k_t<<<dim3(E, 16, ZT), 64, 0, stream>>>(Hbf, mxT, perm, offs, tpart);
  k_tred<<<256, 256, 0, stream>>>(tpart, tbuf);
  k_inter<<<dim3(E, 16, P / 256), 256, 0, stream>>>(tbuf, Aubf, Agbf, offs, inter);
  k_down<<<dim3(E, KSPLIT, D / 64), 256, 0, stream>>>(inter, Wd, offs, dpart);
  k_red<<<256, 256, 0, stream>>>(dpart, perm, wts, out);
}

// Round 5
// 214.938 us; speedup vs baseline: 1.8429x; 1.0125x over previous
//
#include <hip/hip_runtime.h>
#include <hip/hip_bf16.h>
#include <math.h>

#define S 1024
#define D 1024
#define P 2816
#define R 64
#define E 8
#define M 16
#define KSPLIT 4
#define KQ (P / KSPLIT)        // 704
#define NIT (KQ / 64)          // 11
#define ZT 16                  // k_t K-split; slice = D/ZT = 64
#define ACH ((E * P * R) / 8)  // 180224 adapter short8-chunks

typedef __attribute__((ext_vector_type(8))) short short8;   // 8 bf16 (4 VGPRs)
typedef __attribute__((ext_vector_type(4))) float floatx4;  // MFMA acc

static __device__ inline unsigned short f2bf(float f) {
  __hip_bfloat16 h = __float2bfloat16(f);
  return *reinterpret_cast<unsigned short*>(&h);
}
static __device__ inline short8 pack8(float4 a, float4 b) {
  short8 v;
  v[0] = f2bf(a.x); v[1] = f2bf(a.y); v[2] = f2bf(a.z); v[3] = f2bf(a.w);
  v[4] = f2bf(b.x); v[5] = f2bf(b.y); v[6] = f2bf(b.z); v[7] = f2bf(b.w);
  return v;
}

// ---------------------------------------------------------------------------
// K1 (streaming pre-pass), grid 256 x 256:
//  - counting sort (block 0)
//  - H -> bf16 (Hbf), adapters -> bf16 (Aubf/Agbf)   [pure coalesced streams]
// Mix/transpose moved to k_mix (the old fused version did 2M scattered 2B
// stores at 2KB stride = ~128 MB of L2 RMW sector traffic).
// ---------------------------------------------------------------------------
__global__ __launch_bounds__(256) void k_pre(
    const float* __restrict__ H, const float* __restrict__ Aup,
    const float* __restrict__ Agate, const int* __restrict__ idx,
    unsigned short* __restrict__ Hbf, unsigned short* __restrict__ Aubf,
    unsigned short* __restrict__ Agbf, int* __restrict__ perm,
    int* __restrict__ offs) {
  int b = blockIdx.x, t = threadIdx.x;
  int g = b * 256 + t;

  if (b == 0) {  // counting sort, 4 tokens/thread
    __shared__ int hist[E];
    __shared__ int basearr[E];
    if (t < E) hist[t] = 0;
    __syncthreads();
    int e4[4];
#pragma unroll
    for (int j = 0; j < 4; ++j) {
      e4[j] = idx[t + j * 256];
      atomicAdd(&hist[e4[j]], 1);
    }
    __syncthreads();
    if (t == 0) {
      int run = 0;
      for (int i = 0; i < E; ++i) { basearr[i] = run; offs[i] = run; run += hist[i]; }
      offs[E] = S;
    }
    __syncthreads();
#pragma unroll
    for (int j = 0; j < 4; ++j) {
      int pos = atomicAdd(&basearr[e4[j]], 1);
      perm[pos] = t + j * 256;
    }
  }

  // H -> bf16, 16 elems/thread (coalesced)
  {
    const float* hs = H + (size_t)g * 16;
    float4 h0 = *(const float4*)hs, h1 = *(const float4*)(hs + 4);
    float4 h2 = *(const float4*)(hs + 8), h3 = *(const float4*)(hs + 12);
    *(short8*)(Hbf + (size_t)g * 16) = pack8(h0, h1);
    *(short8*)(Hbf + (size_t)g * 16 + 8) = pack8(h2, h3);
  }
  // adapters -> bf16 (grid-stride over short8 chunks)
#pragma unroll
  for (int j = 0; j < 3; ++j) {
    int c = g + j * 65536;
    if (c < ACH) {
      const float* su = Aup + (size_t)c * 8;
      const float* sg = Agate + (size_t)c * 8;
      float4 u0 = *(const float4*)su, u1 = *(const float4*)(su + 4);
      float4 g0 = *(const float4*)sg, g1 = *(const float4*)(sg + 4);
      *(short8*)(Aubf + (size_t)c * 8) = pack8(u0, u1);
      *(short8*)(Agbf + (size_t)c * 8) = pack8(g0, g1);
    }
  }
}

// ---------------------------------------------------------------------------
// K1b: mixed bases, transposed via LDS. grid (2 mats, D/16=64), block 256.
// Reads: bank[m][d][r] float4-coalesced over r -- each bank element read
// exactly ONCE (8 MB total). All 8 experts accumulated in registers
// (16 loads + 512 FMA / thread). Writes: mxT[e][n][d0..d0+16) in contiguous
// 32B row-chunks (vs the old 2B/2KB-stride scatter).
// ---------------------------------------------------------------------------
__global__ __launch_bounds__(256) void k_mix(
    const float* __restrict__ up_logits, const float* __restrict__ gate_logits,
    const float* __restrict__ up_bank, const float* __restrict__ gate_bank,
    unsigned short* __restrict__ mxT) {
  int mat = blockIdx.x;
  int d0 = blockIdx.y * 16;
  const float* bank = mat ? gate_bank : up_bank;
  __shared__ float alpha[E][M];
  __shared__ float tile[E][64][17];  // [e][r][d-local], +1 pad
  int t = threadIdx.x;
  if (t < E) {
    const float* lg = (mat ? gate_logits : up_logits) + t * M;
    float v[M], mx = -1e30f, s = 0.f;
#pragma unroll
    for (int m = 0; m < M; ++m) { v[m] = lg[m]; mx = fmaxf(mx, v[m]); }
#pragma unroll
    for (int m = 0; m < M; ++m) { v[m] = expf(v[m] - mx); s += v[m]; }
#pragma unroll
    for (int m = 0; m < M; ++m) alpha[t][m] = v[m] / s;
  }
  __syncthreads();
  int r4 = (t & 15) * 4;  // r base: thread covers r4..r4+3
  int dg = t >> 4;        // d-local 0..15
  float val[E][4];
#pragma unroll
  for (int e = 0; e < E; ++e)
#pragma unroll
    for (int i = 0; i < 4; ++i) val[e][i] = 0.f;
  for (int m = 0; m < M; ++m) {
    float4 bv = *(const float4*)(bank + ((size_t)m * D + d0 + dg) * R + r4);
#pragma unroll
    for (int e = 0; e < E; ++e) {
      float a = alpha[e][m];
      val[e][0] += a * bv.x; val[e][1] += a * bv.y;
      val[e][2] += a * bv.z; val[e][3] += a * bv.w;
    }
  }
#pragma unroll
  for (int e = 0; e < E; ++e)
#pragma unroll
    for (int i = 0; i < 4; ++i) tile[e][r4 + i][dg] = val[e][i];
  __syncthreads();
  int e = t >> 5;
#pragma unroll
  for (int half = 0; half < 2; ++half) {
    int rr = (t & 31) + half * 32;
    short8 o0, o1;
#pragma unroll
    for (int j = 0; j < 8; ++j) {
      o0[j] = (short)f2bf(tile[e][rr][j]);
      o1[j] = (short)f2bf(tile[e][rr][8 + j]);
    }
    unsigned short* dst = mxT + ((size_t)(e * 128 + mat * 64 + rr)) * D + d0;
    *(short8*)dst = o0;
    *(short8*)(dst + 8) = o1;
  }
}

// ---------------------------------------------------------------------------
// K2: t-partials. ONE WAVE per block (64 threads): 16 tok x 128 n x K=64.
// grid (E, 16 tok-tiles of 16, ZT=16 K-slices) = 2048 blocks (~2 waves/SIMD).
// No LDS, no barriers, no atomics: f32 partials tpart[z][pos][n].
// ---------------------------------------------------------------------------
__global__ __launch_bounds__(64) void k_t(
    const unsigned short* __restrict__ Hbf, const unsigned short* __restrict__ mxT,
    const int* __restrict__ perm, const int* __restrict__ offs,
    float* __restrict__ tpart) {
  int e = blockIdx.x;
  int end = offs[e + 1];
  int row0 = offs[e] + blockIdx.y * 16;
  if (row0 >= end) return;
  int lane = threadIdx.x & 63;
  int quad = lane >> 4, l15 = lane & 15;
  int z = blockIdx.z;
  int k0 = z * (D / ZT);
  int pos = row0 + l15;
  int tok = (pos < end) ? perm[pos] : -1;
  const unsigned short* hrow = Hbf + (size_t)(tok < 0 ? 0 : tok) * D + k0;
  const unsigned short* brow = mxT + (size_t)e * 128 * D + k0;
  floatx4 acc[8];
#pragma unroll
  for (int nt = 0; nt < 8; ++nt) acc[nt] = (floatx4){0.f, 0.f, 0.f, 0.f};
#pragma unroll
  for (int ks = 0; ks < 2; ++ks) {  // K = 64 = 2 x 32
    int kc = ks * 32 + quad * 8;
    short8 a = (short8){0, 0, 0, 0, 0, 0, 0, 0};
    if (tok >= 0) a = *(const short8*)(hrow + kc);
#pragma unroll
    for (int nt = 0; nt < 8; ++nt) {
      short8 bb = *(const short8*)(brow + (size_t)(nt * 16 + l15) * D + kc);
      acc[nt] = __builtin_amdgcn_mfma_f32_16x16x32_bf16(a, bb, acc[nt], 0, 0, 0);
    }
  }
#pragma unroll
  for (int reg = 0; reg < 4; ++reg) {
    int p = row0 + quad * 4 + reg;
    if (p < end) {
#pragma unroll
      for (int nt = 0; nt < 8; ++nt)
        tpart[((size_t)z * S + p) * 128 + nt * 16 + l15] = acc[nt][reg];
    }
  }
}

// K2b: reduce ZT partials -> tbuf bf16. grid 256 x 256, 2 elems/thread.
__global__ __launch_bounds__(256) void k_tred(
    const float* __restrict__ tpart, unsigned short* __restrict__ tbuf) {
  int i = (blockIdx.x * 256 + threadIdx.x) * 2;
  float2 s = make_float2(0.f, 0.f);
#pragma unroll
  for (int z = 0; z < ZT; ++z) {
    float2 v = *(const float2*)(tpart + (size_t)z * S * 128 + i);
    s.x += v.x; s.y += v.y;
  }
  unsigned int pk = (unsigned int)f2bf(s.x) | ((unsigned int)f2bf(s.y) << 16);
  *(unsigned int*)(tbuf + i) = pk;
}

// ---------------------------------------------------------------------------
// K3: inter[pos, p] = silu(t_g @ Ag[p]) * (t_u @ Au[p]), bf16 out.
// No LDS, no barriers, direct stores. grid (E, 16 tok-tiles of 16, P/256=11),
// block = 4 indep waves of 16 tok x 64 p.
// ---------------------------------------------------------------------------
__global__ __launch_bounds__(256) void k_inter(
    const unsigned short* __restrict__ tbuf, const unsigned short* __restrict__ Aubf,
    const unsigned short* __restrict__ Agbf, const int* __restrict__ offs,
    unsigned short* __restrict__ inter) {
  int e = blockIdx.x;
  int start = offs[e] + blockIdx.y * 16;
  int end = offs[e + 1];
  if (start >= end) return;
  int t = threadIdx.x, lane = t & 63, w = t >> 6;
  int quad = lane >> 4, l15 = lane & 15;
  int p0 = blockIdx.z * 256 + w * 64;
  int pos = start + l15;
  bool okA = pos < end;
  floatx4 accu[4], accg[4];
#pragma unroll
  for (int nt = 0; nt < 4; ++nt) {
    accu[nt] = (floatx4){0.f, 0.f, 0.f, 0.f};
    accg[nt] = (floatx4){0.f, 0.f, 0.f, 0.f};
  }
#pragma unroll
  for (int ks = 0; ks < 2; ++ks) {
    int kc = ks * 32 + quad * 8;
    short8 au = (short8){0, 0, 0, 0, 0, 0, 0, 0};
    short8 ag = (short8){0, 0, 0, 0, 0, 0, 0, 0};
    if (okA) {
      au = *(const short8*)(tbuf + (size_t)pos * 128 + kc);
      ag = *(const short8*)(tbuf + (size_t)pos * 128 + 64 + kc);
    }
#pragma unroll
    for (int nt = 0; nt < 4; ++nt) {
      size_t prow = (size_t)e * P + p0 + nt * 16 + l15;
      short8 bu = *(const short8*)(Aubf + prow * R + kc);
      short8 bg = *(const short8*)(Agbf + prow * R + kc);
      accu[nt] = __builtin_amdgcn_mfma_f32_16x16x32_bf16(au, bu, accu[nt], 0, 0, 0);
      accg[nt] = __builtin_amdgcn_mfma_f32_16x16x32_bf16(ag, bg, accg[nt], 0, 0, 0);
    }
  }
#pragma unroll
  for (int nt = 0; nt < 4; ++nt)
#pragma unroll
    for (int reg = 0; reg < 4; ++reg) {
      int prow = start + quad * 4 + reg;
      if (prow < end) {
        float gv = accg[nt][reg], uv = accu[nt][reg];
        float val = uv * (gv / (1.f + __expf(-gv)));
        inter[(size_t)prow * P + p0 + nt * 16 + l15] = f2bf(val);
      }
    }
}

// ---------------------------------------------------------------------------
// K4: down-projection partials -- UNCHANGED from round 4 (fell out of top-5,
// i.e. < 53 us; atomics were the old 54-us floor). Plain coalesced stores of
// K-split partials into pos-space dpart[kz][pos][d].
// grid (E, KSPLIT=4, D/64=16), block 256. Tile 256 tok x 64 d, BK=64.
// ---------------------------------------------------------------------------
__global__ __launch_bounds__(256) void k_down(
    const unsigned short* __restrict__ inter, const float* __restrict__ Wd,
    const int* __restrict__ offs, float* __restrict__ dpart) {
  int e = blockIdx.x;
  int start = offs[e];
  int end = offs[e + 1];
  if (start >= end) return;
  int kz = blockIdx.y;
  int d0 = blockIdx.z * 64;
  __shared__ unsigned short As[256][72];  // 36.9 KB
  __shared__ unsigned short Bs[64][72];   //  9.2 KB
  int t = threadIdx.x;
  int lane = t & 63, w = t >> 6, quad = lane >> 4, l15 = lane & 15;

  // A staging: 8 chunks/thread; fixed col (t&7)*8, rows (t>>3)+32j
  const unsigned short* aptr[8];
  bool aok[8];
#pragma unroll
  for (int j = 0; j < 8; ++j) {
    int arow = (t >> 3) + 32 * j;
    int pos = start + arow;
    aok[j] = (pos < end);
    aptr[j] = inter + (size_t)(aok[j] ? pos : start) * P + kz * KQ + (t & 7) * 8;
  }
  // B staging: row t>>2, cols (t&3)*16 .. +16 (fp32)
  const float* bsrc = Wd + ((size_t)(e * D + d0 + (t >> 2)) * P + kz * KQ + (t & 3) * 16);

  float4 pa[8];
  float4 pb[4];
#pragma unroll
  for (int j = 0; j < 8; ++j)
    pa[j] = aok[j] ? *(const float4*)(aptr[j]) : make_float4(0.f, 0.f, 0.f, 0.f);
#pragma unroll
  for (int q = 0; q < 4; ++q) pb[q] = *(const float4*)(bsrc + q * 4);

  floatx4 acc[4][4];
#pragma unroll
  for (int tt = 0; tt < 4; ++tt)
#pragma unroll
    for (int dt = 0; dt < 4; ++dt) acc[tt][dt] = (floatx4){0.f, 0.f, 0.f, 0.f};

  for (int it = 0; it < NIT; ++it) {
    // write staged registers to LDS (compiler inserts the vmcnt wait)
#pragma unroll
    for (int j = 0; j < 8; ++j)
      *(float4*)&As[(t >> 3) + 32 * j][(t & 7) * 8] = pa[j];
    {
      short8 bv0, bv1;
      bv0[0] = f2bf(pb[0].x); bv0[1] = f2bf(pb[0].y); bv0[2] = f2bf(pb[0].z); bv0[3] = f2bf(pb[0].w);
      bv0[4] = f2bf(pb[1].x); bv0[5] = f2bf(pb[1].y); bv0[6] = f2bf(pb[1].z); bv0[7] = f2bf(pb[1].w);
      bv1[0] = f2bf(pb[2].x); bv1[1] = f2bf(pb[2].y); bv1[2] = f2bf(pb[2].z); bv1[3] = f2bf(pb[2].w);
      bv1[4] = f2bf(pb[3].x); bv1[5] = f2bf(pb[3].y); bv1[6] = f2bf(pb[3].z); bv1[7] = f2bf(pb[3].w);
      *(short8*)&Bs[t >> 2][(t & 3) * 16] = bv0;
      *(short8*)&Bs[t >> 2][(t & 3) * 16 + 8] = bv1;
    }
    __syncthreads();
    // prefetch next iteration's tiles (overlaps with MFMA below)
    if (it + 1 < NIT) {
      int k0 = (it + 1) * 64;
#pragma unroll
      for (int j = 0; j < 8; ++j)
        pa[j] = aok[j] ? *(const float4*)(aptr[j] + k0) : make_float4(0.f, 0.f, 0.f, 0.f);
#pragma unroll
      for (int q = 0; q < 4; ++q) pb[q] = *(const float4*)(bsrc + k0 + q * 4);
    }
#pragma unroll
    for (int ks = 0; ks < 2; ++ks) {
      int kc = ks * 32 + quad * 8;
      short8 a[4], b[4];
#pragma unroll
      for (int tt = 0; tt < 4; ++tt) a[tt] = *(const short8*)&As[w * 64 + tt * 16 + l15][kc];
#pragma unroll
      for (int dt = 0; dt < 4; ++dt) b[dt] = *(const short8*)&Bs[dt * 16 + l15][kc];
#pragma unroll
      for (int tt = 0; tt < 4; ++tt)
#pragma unroll
        for (int dt = 0; dt < 4; ++dt)
          acc[tt][dt] = __builtin_amdgcn_mfma_f32_16x16x32_bf16(a[tt], b[dt], acc[tt][dt], 0, 0, 0);
    }
    __syncthreads();
  }
  float* dp = dpart + (size_t)kz * S * D;
#pragma unroll
  for (int tt = 0; tt < 4; ++tt)
#pragma unroll
    for (int reg = 0; reg < 4; ++reg) {
      int pos = start + w * 64 + tt * 16 + quad * 4 + reg;
      if (pos < end) {
#pragma unroll
        for (int dt = 0; dt < 4; ++dt)
          dp[(size_t)pos * D + d0 + dt * 16 + l15] = acc[tt][dt][reg];
      }
    }
}

// ---------------------------------------------------------------------------
// K5: out[perm[pos], d] = wts[perm[pos]] * sum_kz dpart[kz][pos][d].
// 16 MB read + 4 MB write, coalesced lanes over d; grid 256 x 256, 4 rows/blk.
// ---------------------------------------------------------------------------
__global__ __launch_bounds__(256) void k_red(
    const float* __restrict__ dpart, const int* __restrict__ perm,
    const float* __restrict__ wts, float* __restrict__ out) {
  int t = threadIdx.x;
  int row = blockIdx.x * 4 + (t >> 6);
  int lane = t & 63;
  int tok = perm[row];
  float wt = wts[tok];
  const float* src = dpart + (size_t)row * D + lane * 4;
  float* dst = out + (size_t)tok * D + lane * 4;
#pragma unroll
  for (int j = 0; j < 4; ++j) {
    float4 s = *(const float4*)(src + j * 256);
#pragma unroll
    for (int kz = 1; kz < KSPLIT; ++kz) {
      float4 v = *(const float4*)(src + (size_t)kz * S * D + j * 256);
      s.x += v.x; s.y += v.y; s.z += v.z; s.w += v.w;
    }
    s.x *= wt; s.y *= wt; s.z *= wt; s.w *= wt;
    *(float4*)(dst + j * 256) = s;
  }
}

// ---------------------------------------------------------------------------
extern "C" void kernel_launch(void* const* d_in, const int* in_sizes, int n_in,
                              void* d_out, int out_size, void* d_ws, size_t ws_size,
                              hipStream_t stream) {
  const float* H = (const float*)d_in[0];
  const int* idx = (const int*)d_in[1];
  const float* wts = (const float*)d_in[2];
  const float* Aup = (const float*)d_in[3];
  const float* Agate = (const float*)d_in[4];
  const float* upl = (const float*)d_in[5];
  const float* gatel = (const float*)d_in[6];
  const float* Wd = (const float*)d_in[7];
  const float* upb = (const float*)d_in[8];
  const float* gateb = (const float*)d_in[9];
  float* out = (float*)d_out;

  char* ws = (char*)d_ws;
  unsigned short* Hbf = (unsigned short*)ws;                  // S*D bf16 = 2 MB
  unsigned short* mxT = Hbf + (size_t)S * D;                  // E*128*D bf16 = 2 MB
  unsigned short* Aubf = mxT + (size_t)E * 128 * D;           // E*P*R bf16 = 2.9 MB
  unsigned short* Agbf = Aubf + (size_t)E * P * R;            // 2.9 MB
  unsigned short* inter = Agbf + (size_t)E * P * R;           // S*P bf16 = 5.8 MB
  unsigned short* tbuf = inter + (size_t)S * P;               // S*128 bf16 = 256 KB
  float* tpart = (float*)(tbuf + (size_t)S * 128);            // ZT*S*128 f32 = 8 MB
  float* dpart = tpart + (size_t)ZT * S * 128;                // KSPLIT*S*D f32 = 16 MB
  int* perm = (int*)(dpart + (size_t)KSPLIT * S * D);
  int* offs = perm + S;

  k_pre<<<256, 256, 0, stream>>>(H, Aup, Agate, idx, Hbf, Aubf, Agbf, perm, offs);
  k_mix<<<dim3(2, D / 16), 256, 0, stream>>>(upl, gatel, upb, gateb, mxT);
  k_t<<<dim3(E, 16, ZT), 64, 0, stream>>>(Hbf, mxT, perm, offs, tpart);
  k_tred<<<256, 256, 0, stream>>>(tpart, tbuf);
  k_inter<<<dim3(E, 16, P / 256), 256, 0, stream>>>(tbuf, Aubf, Agbf, offs, inter);
  k_down<<<dim3(E, KSPLIT, D / 64), 256, 0, stream>>>(inter, Wd, offs, dpart);
  k_red<<<256, 256, 0, stream>>>(dpart, perm, wts, out);
}